// Round 6
// baseline (126.021 us; speedup 1.0000x reference)
//
#include <hip/hip_runtime.h>
#include <math.h>

#define F_    16
#define NV_   4096
#define NT_   512
#define M_    4096
#define PPF_  (NV_ + NT_)        // 4608 points per frame
#define NPTS_ (F_ * PPF_)        // 73728 total points
#define SCALE_INV 10.0f          // 1 / 0.1

#define TPB    256               // prep / reduce / fallback block size
#define TPB_M  128               // main block size
#define PPT    8                 // points per thread (main)
#define PPB    (TPB_M * PPT)     // 1024 points per block
#define NPB    (NPTS_ / PPB)     // 72 point-blocks
#define CHUNK  128               // model points per chunk
#define NCHUNK (M_ / CHUNK)      // 32 chunks -> grid 72x32 = 2304 blocks (9/CU)
#define NRB    (NPTS_ / TPB)     // 288 reduce blocks

// ws layout (16B-aligned regions):
//   [0]     float acc, [4] uint ticket
//   [256]   float4 feat[M_]        (64 KiB)  {-2g, |g|^2}
//   [65792] float poses[F_*12]     (768 B)   t + R*SCALE_INV
//   [66816] float partials[NCHUNK][NPTS_]   (9.4 MB)
#define WS_FEAT_OFF  256
#define WS_POSE_OFF  (WS_FEAT_OFF + M_ * 16)
#define WS_PART_OFF  (WS_POSE_OFF + 1024)
#define WS_NEED      (WS_PART_OFF + (size_t)NCHUNK * NPTS_ * 4)

// ---------------------------------------------------------------- pose math
__device__ inline void rot_from_omega(float ox, float oy, float oz, float dt,
                                      float* R) {
    // R = I + sin(theta*dt)*S + (1-cos(theta*dt))*S^2,  S = skew(omega/max(theta,1e-8))
    float theta = sqrtf(ox * ox + oy * oy + oz * oz);
    float inv = 1.0f / fmaxf(theta, 1e-8f);
    float ax = ox * inv, ay = oy * inv, az = oz * inv;
    float s = sinf(theta * dt);
    float c = 1.0f - cosf(theta * dt);
    R[0] = 1.0f - c * (ay * ay + az * az);
    R[1] = -s * az + c * ax * ay;
    R[2] =  s * ay + c * ax * az;
    R[3] =  s * az + c * ax * ay;
    R[4] = 1.0f - c * (ax * ax + az * az);
    R[5] = -s * ax + c * ay * az;
    R[6] = -s * ay + c * ax * az;
    R[7] =  s * ax + c * ay * az;
    R[8] = 1.0f - c * (ax * ax + ay * ay);
}

// ---------------------------------------------------------------- prep
// 5 blocks: 0..3 build the model feature table; 4 computes poses (parallel
// transcendentals, thread-0 cheap compose) + zeroes acc/ticket.
__global__ __launch_bounds__(TPB) void prep_kernel(
    const float* __restrict__ state, const float* __restrict__ model,
    const float* __restrict__ phys, const float* __restrict__ dts,
    float* __restrict__ ws) {
    const int tid = threadIdx.x;
    if (blockIdx.x < 4) {
        float4* __restrict__ feat = (float4*)((char*)ws + WS_FEAT_OFF);
#pragma unroll
        for (int j = 0; j < 4; ++j) {
            int i = blockIdx.x * 1024 + j * TPB + tid;
            float gx = model[i * 3 + 0];
            float gy = model[i * 3 + 1];
            float gz = model[i * 3 + 2];
            feat[i] = make_float4(-2.0f * gx, -2.0f * gy, -2.0f * gz,
                                  gx * gx + gy * gy + gz * gz);
        }
        return;
    }
    // pose block
    __shared__ float sRs[F_ * 9];
    __shared__ float sdt[F_ * 3];
    if (tid == 32) { ws[0] = 0.0f; ((unsigned*)ws)[1] = 0u; }
    if (tid < F_) {
        float Rs[9];
        if (tid == 0) {
            rot_from_omega(state[3], state[4], state[5], 1.0f, Rs);
        } else {
            float dt = dts[tid];
            rot_from_omega(phys[tid * 12 + 9], phys[tid * 12 + 10],
                           phys[tid * 12 + 11], dt, Rs);
            sdt[tid * 3 + 0] = phys[tid * 12 + 6] * dt;
            sdt[tid * 3 + 1] = phys[tid * 12 + 7] * dt;
            sdt[tid * 3 + 2] = phys[tid * 12 + 8] * dt;
        }
        for (int j = 0; j < 9; ++j) sRs[tid * 9 + j] = Rs[j];
    }
    __syncthreads();
    if (tid == 0) {
        float* poses = (float*)((char*)ws + WS_POSE_OFF);
        float t[3] = {state[0], state[1], state[2]};
        float R[9];
        for (int j = 0; j < 9; ++j) R[j] = sRs[j];
        for (int i = 0; i < F_; ++i) {
            if (i > 0) {
                t[0] += sdt[i * 3 + 0];
                t[1] += sdt[i * 3 + 1];
                t[2] += sdt[i * 3 + 2];
                float Rn[9];
                const float* Rs = sRs + i * 9;
                for (int r = 0; r < 3; ++r)
                    for (int c2 = 0; c2 < 3; ++c2)
                        Rn[r * 3 + c2] = Rs[r * 3 + 0] * R[0 + c2] +
                                         Rs[r * 3 + 1] * R[3 + c2] +
                                         Rs[r * 3 + 2] * R[6 + c2];
                for (int j = 0; j < 9; ++j) R[j] = Rn[j];
            }
            float* o = poses + i * 12;
            o[0] = t[0]; o[1] = t[1]; o[2] = t[2];
            for (int j = 0; j < 9; ++j) o[3 + j] = R[j] * SCALE_INV;  // fold 1/SCALE
        }
    }
}

// helper: per-group distance update (4 model features vs 8 points)
#define COMPUTE_GROUP(G0, G1, G2, G3)                                           \
    _Pragma("unroll")                                                           \
    for (int k = 0; k < PPT; ++k) {                                             \
        float d0 = fmaf(G0.x, c0[k], fmaf(G0.y, c1[k], fmaf(G0.z, c2[k], G0.w)));\
        float d1 = fmaf(G1.x, c0[k], fmaf(G1.y, c1[k], fmaf(G1.z, c2[k], G1.w)));\
        float d2 = fmaf(G2.x, c0[k], fmaf(G2.y, c1[k], fmaf(G2.z, c2[k], G2.w)));\
        float d3 = fmaf(G3.x, c0[k], fmaf(G3.y, c1[k], fmaf(G3.z, c2[k], G3.w)));\
        dm[k] = fminf(dm[k], fminf(fminf(d0, d1), fminf(d2, d3)));              \
    }

// ---------------------------------------------------------------- main
// grid (NPB, NCHUNK) = (72, 32). Explicit ping-pong prefetch: group B's loads
// issue before group A's compute, so ~240 cyc of FMA covers the load latency.
__global__ __launch_bounds__(TPB_M, 5) void chamfer_main(
    const float4* __restrict__ feat, const float* __restrict__ poses,
    const float* __restrict__ vis, const float* __restrict__ tac,
    float* __restrict__ partials) {
    __shared__ float sposes[F_ * 12];
    const int tid = threadIdx.x;
    const int pb = blockIdx.x;
    const int ch = blockIdx.y;
    const float4* __restrict__ fb = feat + ch * CHUNK;

    for (int i = tid; i < F_ * 12; i += TPB_M) sposes[i] = poses[i];
    __syncthreads();

    // transform this thread's 8 points: c = (p - t) @ (R/SCALE)
    float c0[PPT], c1[PPT], c2[PPT], cn[PPT], dm[PPT];
#pragma unroll
    for (int k = 0; k < PPT; ++k) {
        int pt = pb * PPB + k * TPB_M + tid;
        int f = pt / PPF_;
        int loc = pt - f * PPF_;
        const float* p = (loc < NV_) ? (vis + ((size_t)f * NV_ + loc) * 3)
                                     : (tac + ((size_t)f * NT_ + (loc - NV_)) * 3);
        float px = p[0], py = p[1], pz = p[2];
        const float* ps = sposes + f * 12;
        float d0 = px - ps[0], d1 = py - ps[1], d2 = pz - ps[2];
        const float* R = ps + 3;
        float x = d0 * R[0] + d1 * R[3] + d2 * R[6];
        float y = d0 * R[1] + d1 * R[4] + d2 * R[7];
        float z = d0 * R[2] + d1 * R[5] + d2 * R[8];
        c0[k] = x; c1[k] = y; c2[k] = z;
        cn[k] = x * x + y * y + z * z;
        dm[k] = 3.4e38f;
    }

    // software-pipelined min over chunk: min(a.c + b); |c|^2 added at the end
    float4 A0 = fb[0], A1 = fb[1], A2 = fb[2], A3 = fb[3];
    float4 B0, B1, B2, B3;
    for (int m = 0; m < CHUNK - 8; m += 8) {
        B0 = fb[m + 4]; B1 = fb[m + 5]; B2 = fb[m + 6]; B3 = fb[m + 7];
        COMPUTE_GROUP(A0, A1, A2, A3)
        A0 = fb[m + 8]; A1 = fb[m + 9]; A2 = fb[m + 10]; A3 = fb[m + 11];
        COMPUTE_GROUP(B0, B1, B2, B3)
    }
    B0 = fb[CHUNK - 4]; B1 = fb[CHUNK - 3]; B2 = fb[CHUNK - 2]; B3 = fb[CHUNK - 1];
    COMPUTE_GROUP(A0, A1, A2, A3)
    COMPUTE_GROUP(B0, B1, B2, B3)

#pragma unroll
    for (int k = 0; k < PPT; ++k) {
        int pt = pb * PPB + k * TPB_M + tid;
        partials[(size_t)ch * NPTS_ + pt] = dm[k] + cn[k];
    }
}

// ---------------------------------------------------------------- reduce
__global__ __launch_bounds__(TPB) void chamfer_reduce(
    const float* __restrict__ partials, float* __restrict__ acc,
    float* __restrict__ out) {
    int pt = blockIdx.x * TPB + threadIdx.x;   // grid = NRB = 288
    float m = partials[pt];
    for (int ch = 1; ch < NCHUNK; ++ch)
        m = fminf(m, partials[(size_t)ch * NPTS_ + pt]);
    int loc = pt % PPF_;
    float w = (loc < NV_) ? (1.0f / NV_) : (0.1f / NT_);
    float v = m * w;
#pragma unroll
    for (int off = 32; off > 0; off >>= 1) v += __shfl_down(v, off);
    __shared__ float sw[TPB / 64];
    if ((threadIdx.x & 63) == 0) sw[threadIdx.x >> 6] = v;
    __syncthreads();
    if (threadIdx.x == 0) {
        float s = 0.0f;
        for (int i = 0; i < TPB / 64; ++i) s += sw[i];
        atomicAdd(&acc[0], s);
        __threadfence();
        unsigned ticket = atomicAdd((unsigned*)&acc[1], 1u);
        if (ticket == NRB - 1) {
            float tot = atomicAdd(&acc[0], 0.0f);  // coherent read at L2 point
            out[0] = tot;
        }
    }
}

// ---------------------------------------------------------------- zero-ws fallback
#define FB_PPT  2
#define FB_PPB  (TPB * FB_PPT)
#define FB_NPB  (NPTS_ / FB_PPB)   // 144 blocks

__device__ inline void compute_pose_serial(int f, const float* state,
                                           const float* phys, const float* dts,
                                           float* t, float* R) {
    t[0] = state[0]; t[1] = state[1]; t[2] = state[2];
    rot_from_omega(state[3], state[4], state[5], 1.0f, R);
    for (int i = 1; i <= f; ++i) {
        float dt = dts[i];
        t[0] += phys[i * 12 + 6] * dt;
        t[1] += phys[i * 12 + 7] * dt;
        t[2] += phys[i * 12 + 8] * dt;
        float Rs[9];
        rot_from_omega(phys[i * 12 + 9], phys[i * 12 + 10], phys[i * 12 + 11], dt, Rs);
        float Rn[9];
        for (int r = 0; r < 3; ++r)
            for (int c2 = 0; c2 < 3; ++c2)
                Rn[r * 3 + c2] = Rs[r * 3 + 0] * R[0 + c2] +
                                 Rs[r * 3 + 1] * R[3 + c2] +
                                 Rs[r * 3 + 2] * R[6 + c2];
        for (int j = 0; j < 9; ++j) R[j] = Rn[j];
    }
}

__global__ __launch_bounds__(TPB) void chamfer_fused(
    const float* __restrict__ state, const float* __restrict__ model,
    const float* __restrict__ vis, const float* __restrict__ tac,
    const float* __restrict__ phys, const float* __restrict__ dts,
    float* __restrict__ out) {
    __shared__ float4 sfeat[CHUNK];
    __shared__ float sposes[F_ * 12];
    __shared__ float sw[TPB / 64];

    if (threadIdx.x < F_) {
        float t[3], R[9];
        compute_pose_serial(threadIdx.x, state, phys, dts, t, R);
        float* o = sposes + threadIdx.x * 12;
        o[0] = t[0]; o[1] = t[1]; o[2] = t[2];
        for (int j = 0; j < 9; ++j) o[3 + j] = R[j] * SCALE_INV;
    }
    __syncthreads();

    float c0[FB_PPT], c1[FB_PPT], c2[FB_PPT], cn[FB_PPT], dm[FB_PPT], wt[FB_PPT];
#pragma unroll
    for (int k = 0; k < FB_PPT; ++k) {
        int pt = blockIdx.x * FB_PPB + k * TPB + threadIdx.x;
        int f = pt / PPF_;
        int loc = pt - f * PPF_;
        wt[k] = (loc < NV_) ? (1.0f / NV_) : (0.1f / NT_);
        const float* p = (loc < NV_) ? (vis + ((size_t)f * NV_ + loc) * 3)
                                     : (tac + ((size_t)f * NT_ + (loc - NV_)) * 3);
        float px = p[0], py = p[1], pz = p[2];
        const float* ps = sposes + f * 12;
        float d0 = px - ps[0], d1 = py - ps[1], d2 = pz - ps[2];
        const float* R = ps + 3;
        float x = d0 * R[0] + d1 * R[3] + d2 * R[6];
        float y = d0 * R[1] + d1 * R[4] + d2 * R[7];
        float z = d0 * R[2] + d1 * R[5] + d2 * R[8];
        c0[k] = x; c1[k] = y; c2[k] = z;
        cn[k] = x * x + y * y + z * z;
        dm[k] = 3.4e38f;
    }

    for (int ch = 0; ch < NCHUNK; ++ch) {
        __syncthreads();
        if (threadIdx.x < CHUNK) {
            int i = threadIdx.x;
            int mi = ch * CHUNK + i;
            float gx = model[mi * 3 + 0], gy = model[mi * 3 + 1], gz = model[mi * 3 + 2];
            sfeat[i] = make_float4(-2.0f * gx, -2.0f * gy, -2.0f * gz,
                                   gx * gx + gy * gy + gz * gz);
        }
        __syncthreads();
#pragma unroll 4
        for (int m = 0; m < CHUNK; m += 2) {
            float4 ga = sfeat[m];
            float4 gb = sfeat[m + 1];
#pragma unroll
            for (int k = 0; k < FB_PPT; ++k) {
                float da = fmaf(ga.x, c0[k], fmaf(ga.y, c1[k], fmaf(ga.z, c2[k], ga.w)));
                float db = fmaf(gb.x, c0[k], fmaf(gb.y, c1[k], fmaf(gb.z, c2[k], gb.w)));
                dm[k] = fminf(dm[k], fminf(da, db));
            }
        }
    }

    float v = 0.0f;
#pragma unroll
    for (int k = 0; k < FB_PPT; ++k) v += (dm[k] + cn[k]) * wt[k];
#pragma unroll
    for (int off = 32; off > 0; off >>= 1) v += __shfl_down(v, off);
    if ((threadIdx.x & 63) == 0) sw[threadIdx.x >> 6] = v;
    __syncthreads();
    if (threadIdx.x == 0) {
        float s = 0.0f;
        for (int i = 0; i < TPB / 64; ++i) s += sw[i];
        atomicAdd(out, s);
    }
}

// ---------------------------------------------------------------- launch
extern "C" void kernel_launch(void* const* d_in, const int* in_sizes, int n_in,
                              void* d_out, int out_size, void* d_ws, size_t ws_size,
                              hipStream_t stream) {
    const float* state = (const float*)d_in[0];   // (6,)
    const float* model = (const float*)d_in[1];   // (M,3)
    const float* vis   = (const float*)d_in[2];   // (F,NV,3)
    const float* tac   = (const float*)d_in[3];   // (F,NT,3)
    const float* phys  = (const float*)d_in[4];   // (F,12)
    const float* dts   = (const float*)d_in[5];   // (F,)
    float* out = (float*)d_out;

    if (ws_size >= WS_NEED) {
        float* ws = (float*)d_ws;
        const float4* feat = (const float4*)((char*)d_ws + WS_FEAT_OFF);
        const float* poses = (const float*)((char*)d_ws + WS_POSE_OFF);
        float* partials = (float*)((char*)d_ws + WS_PART_OFF);
        prep_kernel<<<5, TPB, 0, stream>>>(state, model, phys, dts, ws);
        dim3 grid(NPB, NCHUNK);
        chamfer_main<<<grid, TPB_M, 0, stream>>>(feat, poses, vis, tac, partials);
        chamfer_reduce<<<NRB, TPB, 0, stream>>>(partials, ws, out);
    } else {
        hipMemsetAsync(out, 0, sizeof(float), stream);
        chamfer_fused<<<FB_NPB, TPB, 0, stream>>>(state, model, vis, tac, phys, dts,
                                                  out);
    }
}

// Round 7
// 105.989 us; speedup vs baseline: 1.1890x; 1.1890x over previous
//
#include <hip/hip_runtime.h>
#include <math.h>

#define F_    16
#define NV_   4096
#define NT_   512
#define M_    4096
#define PPF_  (NV_ + NT_)        // 4608 points per frame
#define NPTS_ (F_ * PPF_)        // 73728 total points
#define SCALE_INV 10.0f          // 1 / 0.1

#define TPB    256               // block size (all kernels)
#define PPT    4                 // points per thread (main) -> 2 packed pairs
#define NPAIR  (PPT / 2)
#define PPB    (TPB * PPT)       // 1024 points per block
#define NPB    (NPTS_ / PPB)     // 72 point-blocks
#define CHUNK  128               // model points per chunk
#define NCHUNK (M_ / CHUNK)      // 32 chunks -> grid 72x32 = 2304 blocks (9/CU)
#define NRB    (NPTS_ / TPB)     // 288 reduce blocks

typedef float v2f __attribute__((ext_vector_type(2)));

static __device__ inline v2f splat2(float s) { v2f r; r.x = s; r.y = s; return r; }

// ws layout (16B-aligned regions):
//   [0]     float acc, [4] uint ticket
//   [256]   float4 feat[M_]        (64 KiB)  {-2g, |g|^2}
//   [65792] float poses[F_*12]     (768 B)   t + R*SCALE_INV
//   [66816] float partials[NCHUNK][NPTS_]   (9.4 MB)
#define WS_FEAT_OFF  256
#define WS_POSE_OFF  (WS_FEAT_OFF + M_ * 16)
#define WS_PART_OFF  (WS_POSE_OFF + 1024)
#define WS_NEED      (WS_PART_OFF + (size_t)NCHUNK * NPTS_ * 4)

// ---------------------------------------------------------------- pose math
__device__ inline void rot_from_omega(float ox, float oy, float oz, float dt,
                                      float* R) {
    // R = I + sin(theta*dt)*S + (1-cos(theta*dt))*S^2,  S = skew(omega/max(theta,1e-8))
    float theta = sqrtf(ox * ox + oy * oy + oz * oz);
    float inv = 1.0f / fmaxf(theta, 1e-8f);
    float ax = ox * inv, ay = oy * inv, az = oz * inv;
    float s = sinf(theta * dt);
    float c = 1.0f - cosf(theta * dt);
    R[0] = 1.0f - c * (ay * ay + az * az);
    R[1] = -s * az + c * ax * ay;
    R[2] =  s * ay + c * ax * az;
    R[3] =  s * az + c * ax * ay;
    R[4] = 1.0f - c * (ax * ax + az * az);
    R[5] = -s * ax + c * ay * az;
    R[6] = -s * ay + c * ax * az;
    R[7] =  s * ax + c * ay * az;
    R[8] = 1.0f - c * (ax * ax + ay * ay);
}

// ---------------------------------------------------------------- prep
// 5 blocks: 0..3 build the model feature table; 4 computes poses (parallel
// transcendentals, thread-0 cheap compose) + zeroes acc/ticket.
__global__ __launch_bounds__(TPB) void prep_kernel(
    const float* __restrict__ state, const float* __restrict__ model,
    const float* __restrict__ phys, const float* __restrict__ dts,
    float* __restrict__ ws) {
    const int tid = threadIdx.x;
    if (blockIdx.x < 4) {
        float4* __restrict__ feat = (float4*)((char*)ws + WS_FEAT_OFF);
#pragma unroll
        for (int j = 0; j < 4; ++j) {
            int i = blockIdx.x * 1024 + j * TPB + tid;
            float gx = model[i * 3 + 0];
            float gy = model[i * 3 + 1];
            float gz = model[i * 3 + 2];
            feat[i] = make_float4(-2.0f * gx, -2.0f * gy, -2.0f * gz,
                                  gx * gx + gy * gy + gz * gz);
        }
        return;
    }
    // pose block
    __shared__ float sRs[F_ * 9];
    __shared__ float sdt[F_ * 3];
    if (tid == 32) { ws[0] = 0.0f; ((unsigned*)ws)[1] = 0u; }
    if (tid < F_) {
        float Rs[9];
        if (tid == 0) {
            rot_from_omega(state[3], state[4], state[5], 1.0f, Rs);
        } else {
            float dt = dts[tid];
            rot_from_omega(phys[tid * 12 + 9], phys[tid * 12 + 10],
                           phys[tid * 12 + 11], dt, Rs);
            sdt[tid * 3 + 0] = phys[tid * 12 + 6] * dt;
            sdt[tid * 3 + 1] = phys[tid * 12 + 7] * dt;
            sdt[tid * 3 + 2] = phys[tid * 12 + 8] * dt;
        }
        for (int j = 0; j < 9; ++j) sRs[tid * 9 + j] = Rs[j];
    }
    __syncthreads();
    if (tid == 0) {
        float* poses = (float*)((char*)ws + WS_POSE_OFF);
        float t[3] = {state[0], state[1], state[2]};
        float R[9];
        for (int j = 0; j < 9; ++j) R[j] = sRs[j];
        for (int i = 0; i < F_; ++i) {
            if (i > 0) {
                t[0] += sdt[i * 3 + 0];
                t[1] += sdt[i * 3 + 1];
                t[2] += sdt[i * 3 + 2];
                float Rn[9];
                const float* Rs = sRs + i * 9;
                for (int r = 0; r < 3; ++r)
                    for (int c2 = 0; c2 < 3; ++c2)
                        Rn[r * 3 + c2] = Rs[r * 3 + 0] * R[0 + c2] +
                                         Rs[r * 3 + 1] * R[3 + c2] +
                                         Rs[r * 3 + 2] * R[6 + c2];
                for (int j = 0; j < 9; ++j) R[j] = Rn[j];
            }
            float* o = poses + i * 12;
            o[0] = t[0]; o[1] = t[1]; o[2] = t[2];
            for (int j = 0; j < 9; ++j) o[3 + j] = R[j] * SCALE_INV;  // fold 1/SCALE
        }
    }
}

// per 2-model-point group, packed across point pairs:
// 6 v_pk_fma_f32 + 4 v_min3_f32 per pair = 2.0 VALU instr per (model,point) pair
#define GRP2(GA, GB)                                                              \
    _Pragma("unroll")                                                             \
    for (int j = 0; j < NPAIR; ++j) {                                             \
        v2f dA = __builtin_elementwise_fma(splat2(GA.x), cx[j],                   \
                 __builtin_elementwise_fma(splat2(GA.y), cy[j],                   \
                 __builtin_elementwise_fma(splat2(GA.z), cz[j], splat2(GA.w))));  \
        v2f dB = __builtin_elementwise_fma(splat2(GB.x), cx[j],                   \
                 __builtin_elementwise_fma(splat2(GB.y), cy[j],                   \
                 __builtin_elementwise_fma(splat2(GB.z), cz[j], splat2(GB.w))));  \
        dm[j] = __builtin_elementwise_min(                                        \
                    __builtin_elementwise_min(dm[j], dA), dB);                    \
    }

// ---------------------------------------------------------------- main
// grid (NPB, NCHUNK) = (72, 32) = 2304 blocks (9/CU). Packed-FP32 inner loop.
__global__ __launch_bounds__(TPB) void chamfer_main(
    const float4* __restrict__ feat, const float* __restrict__ poses,
    const float* __restrict__ vis, const float* __restrict__ tac,
    float* __restrict__ partials) {
    __shared__ float sposes[F_ * 12];
    const int tid = threadIdx.x;
    const int pb = blockIdx.x;
    const int ch = blockIdx.y;
    const float4* __restrict__ fb = feat + ch * CHUNK;  // block-uniform base

    if (tid < F_ * 12) sposes[tid] = poses[tid];
    __syncthreads();

    // transform this thread's 4 points, packed into 2 pairs
    v2f cx[NPAIR], cy[NPAIR], cz[NPAIR], cn[NPAIR], dm[NPAIR];
#pragma unroll
    for (int k = 0; k < PPT; ++k) {
        int pt = pb * PPB + k * TPB + tid;
        int f = pt / PPF_;
        int loc = pt - f * PPF_;
        const float* p = (loc < NV_) ? (vis + ((size_t)f * NV_ + loc) * 3)
                                     : (tac + ((size_t)f * NT_ + (loc - NV_)) * 3);
        float px = p[0], py = p[1], pz = p[2];
        const float* ps = sposes + f * 12;
        float d0 = px - ps[0], d1 = py - ps[1], d2 = pz - ps[2];
        const float* R = ps + 3;
        float x = d0 * R[0] + d1 * R[3] + d2 * R[6];
        float y = d0 * R[1] + d1 * R[4] + d2 * R[7];
        float z = d0 * R[2] + d1 * R[5] + d2 * R[8];
        int j = k >> 1;
        if ((k & 1) == 0) {
            cx[j].x = x; cy[j].x = y; cz[j].x = z;
            cn[j].x = x * x + y * y + z * z; dm[j].x = 3.4e38f;
        } else {
            cx[j].y = x; cy[j].y = y; cz[j].y = z;
            cn[j].y = x * x + y * y + z * z; dm[j].y = 3.4e38f;
        }
    }

    // min over chunk: min(a.c + b); |c|^2 added once at the end.
    // ping-pong prefetch of 2-model groups (features -> scalar regs).
    float4 A0 = fb[0], A1 = fb[1];
    float4 B0, B1;
#pragma unroll 2
    for (int m = 0; m < CHUNK - 4; m += 4) {
        B0 = fb[m + 2]; B1 = fb[m + 3];
        GRP2(A0, A1)
        A0 = fb[m + 4]; A1 = fb[m + 5];
        GRP2(B0, B1)
    }
    B0 = fb[CHUNK - 2]; B1 = fb[CHUNK - 1];
    GRP2(A0, A1)
    GRP2(B0, B1)

#pragma unroll
    for (int k = 0; k < PPT; ++k) {
        int pt = pb * PPB + k * TPB + tid;
        int j = k >> 1;
        float v = ((k & 1) == 0) ? (dm[j].x + cn[j].x) : (dm[j].y + cn[j].y);
        partials[(size_t)ch * NPTS_ + pt] = v;
    }
}

// ---------------------------------------------------------------- reduce
__global__ __launch_bounds__(TPB) void chamfer_reduce(
    const float* __restrict__ partials, float* __restrict__ acc,
    float* __restrict__ out) {
    int pt = blockIdx.x * TPB + threadIdx.x;   // grid = NRB = 288
    float m = partials[pt];
    for (int ch = 1; ch < NCHUNK; ++ch)
        m = fminf(m, partials[(size_t)ch * NPTS_ + pt]);
    int loc = pt % PPF_;
    float w = (loc < NV_) ? (1.0f / NV_) : (0.1f / NT_);
    float v = m * w;
#pragma unroll
    for (int off = 32; off > 0; off >>= 1) v += __shfl_down(v, off);
    __shared__ float sw[TPB / 64];
    if ((threadIdx.x & 63) == 0) sw[threadIdx.x >> 6] = v;
    __syncthreads();
    if (threadIdx.x == 0) {
        float s = 0.0f;
        for (int i = 0; i < TPB / 64; ++i) s += sw[i];
        atomicAdd(&acc[0], s);
        __threadfence();
        unsigned ticket = atomicAdd((unsigned*)&acc[1], 1u);
        if (ticket == NRB - 1) {
            float tot = atomicAdd(&acc[0], 0.0f);  // coherent read at L2 point
            out[0] = tot;
        }
    }
}

// ---------------------------------------------------------------- zero-ws fallback
#define FB_PPT  2
#define FB_PPB  (TPB * FB_PPT)
#define FB_NPB  (NPTS_ / FB_PPB)   // 144 blocks

__device__ inline void compute_pose_serial(int f, const float* state,
                                           const float* phys, const float* dts,
                                           float* t, float* R) {
    t[0] = state[0]; t[1] = state[1]; t[2] = state[2];
    rot_from_omega(state[3], state[4], state[5], 1.0f, R);
    for (int i = 1; i <= f; ++i) {
        float dt = dts[i];
        t[0] += phys[i * 12 + 6] * dt;
        t[1] += phys[i * 12 + 7] * dt;
        t[2] += phys[i * 12 + 8] * dt;
        float Rs[9];
        rot_from_omega(phys[i * 12 + 9], phys[i * 12 + 10], phys[i * 12 + 11], dt, Rs);
        float Rn[9];
        for (int r = 0; r < 3; ++r)
            for (int c2 = 0; c2 < 3; ++c2)
                Rn[r * 3 + c2] = Rs[r * 3 + 0] * R[0 + c2] +
                                 Rs[r * 3 + 1] * R[3 + c2] +
                                 Rs[r * 3 + 2] * R[6 + c2];
        for (int j = 0; j < 9; ++j) R[j] = Rn[j];
    }
}

__global__ __launch_bounds__(TPB) void chamfer_fused(
    const float* __restrict__ state, const float* __restrict__ model,
    const float* __restrict__ vis, const float* __restrict__ tac,
    const float* __restrict__ phys, const float* __restrict__ dts,
    float* __restrict__ out) {
    __shared__ float4 sfeat[CHUNK];
    __shared__ float sposes[F_ * 12];
    __shared__ float sw[TPB / 64];

    if (threadIdx.x < F_) {
        float t[3], R[9];
        compute_pose_serial(threadIdx.x, state, phys, dts, t, R);
        float* o = sposes + threadIdx.x * 12;
        o[0] = t[0]; o[1] = t[1]; o[2] = t[2];
        for (int j = 0; j < 9; ++j) o[3 + j] = R[j] * SCALE_INV;
    }
    __syncthreads();

    float c0[FB_PPT], c1[FB_PPT], c2[FB_PPT], cn[FB_PPT], dm[FB_PPT], wt[FB_PPT];
#pragma unroll
    for (int k = 0; k < FB_PPT; ++k) {
        int pt = blockIdx.x * FB_PPB + k * TPB + threadIdx.x;
        int f = pt / PPF_;
        int loc = pt - f * PPF_;
        wt[k] = (loc < NV_) ? (1.0f / NV_) : (0.1f / NT_);
        const float* p = (loc < NV_) ? (vis + ((size_t)f * NV_ + loc) * 3)
                                     : (tac + ((size_t)f * NT_ + (loc - NV_)) * 3);
        float px = p[0], py = p[1], pz = p[2];
        const float* ps = sposes + f * 12;
        float d0 = px - ps[0], d1 = py - ps[1], d2 = pz - ps[2];
        const float* R = ps + 3;
        float x = d0 * R[0] + d1 * R[3] + d2 * R[6];
        float y = d0 * R[1] + d1 * R[4] + d2 * R[7];
        float z = d0 * R[2] + d1 * R[5] + d2 * R[8];
        c0[k] = x; c1[k] = y; c2[k] = z;
        cn[k] = x * x + y * y + z * z;
        dm[k] = 3.4e38f;
    }

    for (int ch = 0; ch < NCHUNK; ++ch) {
        __syncthreads();
        if (threadIdx.x < CHUNK) {
            int i = threadIdx.x;
            int mi = ch * CHUNK + i;
            float gx = model[mi * 3 + 0], gy = model[mi * 3 + 1], gz = model[mi * 3 + 2];
            sfeat[i] = make_float4(-2.0f * gx, -2.0f * gy, -2.0f * gz,
                                   gx * gx + gy * gy + gz * gz);
        }
        __syncthreads();
#pragma unroll 4
        for (int m = 0; m < CHUNK; m += 2) {
            float4 ga = sfeat[m];
            float4 gb = sfeat[m + 1];
#pragma unroll
            for (int k = 0; k < FB_PPT; ++k) {
                float da = fmaf(ga.x, c0[k], fmaf(ga.y, c1[k], fmaf(ga.z, c2[k], ga.w)));
                float db = fmaf(gb.x, c0[k], fmaf(gb.y, c1[k], fmaf(gb.z, c2[k], gb.w)));
                dm[k] = fminf(dm[k], fminf(da, db));
            }
        }
    }

    float v = 0.0f;
#pragma unroll
    for (int k = 0; k < FB_PPT; ++k) v += (dm[k] + cn[k]) * wt[k];
#pragma unroll
    for (int off = 32; off > 0; off >>= 1) v += __shfl_down(v, off);
    if ((threadIdx.x & 63) == 0) sw[threadIdx.x >> 6] = v;
    __syncthreads();
    if (threadIdx.x == 0) {
        float s = 0.0f;
        for (int i = 0; i < TPB / 64; ++i) s += sw[i];
        atomicAdd(out, s);
    }
}

// ---------------------------------------------------------------- launch
extern "C" void kernel_launch(void* const* d_in, const int* in_sizes, int n_in,
                              void* d_out, int out_size, void* d_ws, size_t ws_size,
                              hipStream_t stream) {
    const float* state = (const float*)d_in[0];   // (6,)
    const float* model = (const float*)d_in[1];   // (M,3)
    const float* vis   = (const float*)d_in[2];   // (F,NV,3)
    const float* tac   = (const float*)d_in[3];   // (F,NT,3)
    const float* phys  = (const float*)d_in[4];   // (F,12)
    const float* dts   = (const float*)d_in[5];   // (F,)
    float* out = (float*)d_out;

    if (ws_size >= WS_NEED) {
        float* ws = (float*)d_ws;
        const float4* feat = (const float4*)((char*)d_ws + WS_FEAT_OFF);
        const float* poses = (const float*)((char*)d_ws + WS_POSE_OFF);
        float* partials = (float*)((char*)d_ws + WS_PART_OFF);
        prep_kernel<<<5, TPB, 0, stream>>>(state, model, phys, dts, ws);
        dim3 grid(NPB, NCHUNK);
        chamfer_main<<<grid, TPB, 0, stream>>>(feat, poses, vis, tac, partials);
        chamfer_reduce<<<NRB, TPB, 0, stream>>>(partials, ws, out);
    } else {
        hipMemsetAsync(out, 0, sizeof(float), stream);
        chamfer_fused<<<FB_NPB, TPB, 0, stream>>>(state, model, vis, tac, phys, dts,
                                                  out);
    }
}